// Round 14
// baseline (10270.175 us; speedup 1.0000x reference)
//
#include <hip/hip_runtime.h>
#include <hip/hip_cooperative_groups.h>
#include <math.h>

#define EPS_MODE 0

namespace cg = cooperative_groups;

typedef unsigned short u16;
typedef short bf16x8 __attribute__((ext_vector_type(8)));
typedef float f32x4 __attribute__((ext_vector_type(4)));
typedef u16 u16x4 __attribute__((ext_vector_type(4)));
typedef u16 u16x8 __attribute__((ext_vector_type(8)));

static constexpr int T = 16;
static constexpr size_t MF = 1u << 20;
static constexpr int DKCH = 512;                // dense split-K chunks
static constexpr int DKCHUNK = 196608 / DKCH;   // 384

__device__ __forceinline__ u16 f2bf(float f) {
  unsigned u = __float_as_uint(f);
  unsigned r = (u + 0x7fffu + ((u >> 16) & 1u)) >> 16;
  return (u16)r;
}
__device__ __forceinline__ float bf2f(u16 h) {
  return __uint_as_float(((unsigned)h) << 16);
}
__device__ __forceinline__ void gload16(const void* g, void* l) {
  __builtin_amdgcn_global_load_lds(
      (const __attribute__((address_space(1))) void*)g,
      (__attribute__((address_space(3))) void*)l, 16, 0, 0);
}
__device__ __forceinline__ float sigm(float x) { return 1.f / (1.f + expf(-x)); }

// ---------------- casts -------------------------------------------------------------
__global__ __launch_bounds__(256) void cast_bf16(const float* __restrict__ in,
                                                 u16* __restrict__ out, int n) {
  int i = (blockIdx.x * 256 + threadIdx.x) * 4;
  if (i < n) {
    float4 v = *reinterpret_cast<const float4*>(&in[i]);
    out[i + 0] = f2bf(v.x); out[i + 1] = f2bf(v.y);
    out[i + 2] = f2bf(v.z); out[i + 3] = f2bf(v.w);
  }
}

// ---------------- W transpose+cast: WT[col][k] --------------------------------------
__global__ __launch_bounds__(256) void prep_wt(const float* __restrict__ Wz0, const float* __restrict__ Wr0,
                                               const float* __restrict__ Wn0, const float* __restrict__ Wz1,
                                               const float* __restrict__ Wr1, const float* __restrict__ Wn1,
                                               u16* __restrict__ WzrT0, u16* __restrict__ WnT0,
                                               u16* __restrict__ WzrT1, u16* __restrict__ WnT1) {
  int seg = blockIdx.y;
  int idx = blockIdx.x * 256 + threadIdx.x;
  if (seg == 0) {
    if (idx < 128 * 64) {
      int j = idx >> 6, k = idx & 63;
      float v = (j < 64) ? Wz0[(k + 1) * 64 + j] : Wr0[(k + 1) * 64 + (j - 64)];
      WzrT0[idx] = f2bf(v);
    }
  } else if (seg == 1) {
    if (idx < 64 * 64) {
      int j = idx >> 6, k = idx & 63;
      WnT0[idx] = f2bf(Wn0[(k + 1) * 64 + j]);
    }
  } else if (seg == 2) {
    if (idx < 256 * 192) {
      int j = idx / 192, k = idx % 192;
      float v = (j < 128) ? Wz1[k * 128 + j] : Wr1[k * 128 + (j - 128)];
      WzrT1[idx] = f2bf(v);
    }
  } else {
    if (idx < 128 * 192) {
      int j = idx / 192, k = idx % 192;
      WnT1[idx] = f2bf(Wn1[k * 128 + j]);
    }
  }
}

// ---------------- t=0 layer-0 closed form -------------------------------------------
__global__ __launch_bounds__(256) void init0(const float* __restrict__ AXv,
                                             const float* __restrict__ Wz0,
                                             const float* __restrict__ bz0,
                                             const float* __restrict__ Wn0,
                                             const float* __restrict__ bn0,
                                             u16* __restrict__ h1T) {
  int b = blockIdx.x, n0 = blockIdx.y * 256;
  __shared__ float axs[256];
  int tid = threadIdx.x;
  if (tid < 64)
    *(float4*)&axs[tid * 4] = *(const float4*)&AXv[((size_t)b << 10) + n0 + tid * 4];
  __syncthreads();
  int cb = tid >> 6, nl = (tid & 63) * 4;
  for (int c0 = 0; c0 < 64; c0 += 4) {
    int c = c0 + cb;
    float wz = Wz0[c], bz = bz0[c], wn = Wn0[c], bn = bn0[c];
    u16x4 pk;
#pragma unroll
    for (int j = 0; j < 4; ++j) {
      float ax = axs[nl + j];
      float z = sigm(fmaf(ax, wz, bz));
      pk[j] = f2bf(z * tanhf(fmaf(ax, wn, bn)));
    }
    *(u16x4*)&h1T[((((size_t)b << 6) + c) << 10) + n0 + nl] = pk;
  }
}

// ---------------- adjacency MFMA GEMM (device) --------------------------------------
template <int EPI, int LOGC, int MFR>
__device__ __forceinline__ void dev_adj_mfma(int bx, int by, char* lds,
                                             const u16* __restrict__ A,
                                             const u16* __restrict__ BT,
                                             void* __restrict__ OUT) {
  constexpr int MT = MFR * 32;
  int tid = threadIdx.x;
  int w = tid >> 6, lane = tid & 63;
  int row0 = by * MT, col0 = bx * 128;
  int wm = w >> 1, wn = w & 1;
  f32x4 acc[MFR][4] = {};
  for (int k0 = 0; k0 < 1024; k0 += 64) {
#pragma unroll
    for (int q = 0; q < MFR; ++q) {
      int row = q * 32 + w * 8 + (lane >> 3);
      gload16(A + (size_t)(row0 + row) * 1024 + k0 + (lane & 7) * 8,
              lds + q * 4096 + w * 1024);
    }
#pragma unroll
    for (int q = 0; q < 4; ++q) {
      int row = q * 32 + w * 8 + (lane >> 3);
      gload16(BT + (size_t)(col0 + row) * 1024 + k0 + (lane & 7) * 8,
              lds + MFR * 4096 + q * 4096 + w * 1024);
    }
    __syncthreads();
#pragma unroll
    for (int kk = 0; kk < 2; ++kk) {
      bf16x8 a[MFR], bb[4];
#pragma unroll
      for (int m = 0; m < MFR; ++m)
        a[m] = *(const bf16x8*)(lds + (wm * (MFR * 16) + m * 16 + (lane & 15)) * 128 + kk * 64 + (lane >> 4) * 16);
#pragma unroll
      for (int n = 0; n < 4; ++n)
        bb[n] = *(const bf16x8*)(lds + MFR * 4096 + (wn * 64 + n * 16 + (lane & 15)) * 128 + kk * 64 + (lane >> 4) * 16);
#pragma unroll
      for (int m = 0; m < MFR; ++m)
#pragma unroll
        for (int n = 0; n < 4; ++n)
          acc[m][n] = __builtin_amdgcn_mfma_f32_16x16x32_bf16(a[m], bb[n], acc[m][n], 0, 0, 0);
    }
    __syncthreads();
  }
  if (EPI == 1) {
    float* O = (float*)OUT;
#pragma unroll
    for (int m = 0; m < MFR; ++m)
#pragma unroll
      for (int n = 0; n < 4; ++n) {
        int col = col0 + wn * 64 + n * 16 + (lane & 15);
        int t = col >> 6, bbx = col & 63;
        int row = row0 + wm * (MFR * 16) + m * 16 + ((lane >> 4) << 2);
        *(float4*)&O[((size_t)t << 16) + ((size_t)bbx << 10) + row] = *(float4*)&acc[m][n];
      }
  } else {
    u16* O = (u16*)OUT;
    constexpr int C = 1 << LOGC;
#pragma unroll
    for (int m = 0; m < MFR; ++m)
#pragma unroll
      for (int n = 0; n < 4; ++n) {
        int col = col0 + wn * 64 + n * 16 + (lane & 15);
        int bbx = col >> LOGC, c = col & (C - 1);
#pragma unroll
        for (int j = 0; j < 4; ++j) {
          int row = row0 + wm * (MFR * 16) + m * 16 + ((lane >> 4) << 2) + j;
          O[(((size_t)bbx << 10) + row) * C + c] = f2bf(acc[m][n][j]);
        }
      }
  }
}

template <int EPI, int LOGC, int MFR>
__global__ __launch_bounds__(256) void adj_mfma(const u16* __restrict__ A,
                                                const u16* __restrict__ BT,
                                                void* __restrict__ OUT) {
  __shared__ __align__(16) char lds[(MFR + 4) * 4096];
  dev_adj_mfma<EPI, LOGC, MFR>(blockIdx.x, blockIdx.y, lds, A, BT, OUT);
}

// ---------------- fused adj@(r*h) + n-gate + GRU update (device) --------------------
template <int C, int RK1, int MFR>
__device__ __forceinline__ void dev_adj_ngate(
    int bx, int by, char* lds,
    const u16* __restrict__ A, const u16* __restrict__ BT,
    const u16* __restrict__ WnT, const float* __restrict__ bias,
    const float* __restrict__ axv, const float* __restrict__ wx,
    const u16* __restrict__ AH1, const u16* __restrict__ zT,
    u16* __restrict__ hT) {
  constexpr int LOGC = (C == 64) ? 6 : 7;
  constexpr int KW = (C == 64) ? 64 : 192;
  constexpr int KKAN = C / 32;
  constexpr int MT = MFR * 32;
  int tid = threadIdx.x;
  int w = tid >> 6, lane = tid & 63;
  int row0 = by * MT, col0 = bx * 128;
  int wm = w >> 1, wn = w & 1;
  f32x4 acc[MFR][4] = {};
  for (int k0 = 0; k0 < 1024; k0 += 64) {
#pragma unroll
    for (int q = 0; q < MFR; ++q) {
      int row = q * 32 + w * 8 + (lane >> 3);
      gload16(A + (size_t)(row0 + row) * 1024 + k0 + (lane & 7) * 8,
              lds + q * 4096 + w * 1024);
    }
#pragma unroll
    for (int q = 0; q < 4; ++q) {
      int row = q * 32 + w * 8 + (lane >> 3);
      gload16(BT + (size_t)(col0 + row) * 1024 + k0 + (lane & 7) * 8,
              lds + MFR * 4096 + q * 4096 + w * 1024);
    }
    __syncthreads();
#pragma unroll
    for (int kk = 0; kk < 2; ++kk) {
      bf16x8 a[MFR], bb[4];
#pragma unroll
      for (int m = 0; m < MFR; ++m)
        a[m] = *(const bf16x8*)(lds + (wm * (MFR * 16) + m * 16 + (lane & 15)) * 128 + kk * 64 + (lane >> 4) * 16);
#pragma unroll
      for (int n = 0; n < 4; ++n)
        bb[n] = *(const bf16x8*)(lds + MFR * 4096 + (wn * 64 + n * 16 + (lane & 15)) * 128 + kk * 64 + (lane >> 4) * 16);
#pragma unroll
      for (int m = 0; m < MFR; ++m)
#pragma unroll
        for (int n = 0; n < 4; ++n)
          acc[m][n] = __builtin_amdgcn_mfma_f32_16x16x32_bf16(a[m], bb[n], acc[m][n], 0, 0, 0);
    }
    __syncthreads();
  }
  u16* ANt = (u16*)lds;
#pragma unroll
  for (int m = 0; m < MFR; ++m)
#pragma unroll
    for (int n = 0; n < 4; ++n) {
      int cl = wn * 64 + n * 16 + (lane & 15);
      int rl = wm * (MFR * 16) + m * 16 + ((lane >> 4) << 2);
#pragma unroll
      for (int j = 0; j < 4; ++j)
        ANt[(rl + j) * 136 + cl] = f2bf(acc[m][n][j]);
    }
  __syncthreads();
  int wrow = w >> 1, half = w & 1;
  int arow0 = wrow * (MFR * 16);
  int b0 = col0 >> LOGC;
  int out0 = (C == 64) ? 0 : half * 64;
  int kbase = (C == 64) ? half * 64 : 0;
  int b_eff = (C == 64) ? (b0 + half) : b0;
  constexpr int WOFF = (C == 64) ? 0 : 64;
  f32x4 acc2[MFR][4] = {};
#pragma unroll
  for (int kk = 0; kk < KKAN; ++kk) {
    bf16x8 a[MFR], bb[4];
    int ka = kbase + kk * 32 + (lane >> 4) * 8;
#pragma unroll
    for (int m = 0; m < MFR; ++m)
      a[m] = *(const bf16x8*)&ANt[(arow0 + m * 16 + (lane & 15)) * 136 + ka];
#pragma unroll
    for (int n = 0; n < 4; ++n)
      bb[n] = *(const bf16x8*)&WnT[(size_t)(out0 + n * 16 + (lane & 15)) * KW + WOFF + kk * 32 + (lane >> 4) * 8];
#pragma unroll
    for (int m = 0; m < MFR; ++m)
#pragma unroll
      for (int n = 0; n < 4; ++n)
        acc2[m][n] = __builtin_amdgcn_mfma_f32_16x16x32_bf16(a[m], bb[n], acc2[m][n], 0, 0, 0);
  }
  if (C == 128) {
#pragma unroll
    for (int kk = 0; kk < 2; ++kk) {
      bf16x8 a[MFR], bb[4];
#pragma unroll
      for (int m = 0; m < MFR; ++m)
        a[m] = *(const bf16x8*)&AH1[(((size_t)b0 << 10) + row0 + arow0 + m * 16 + (lane & 15)) * 64 + kk * 32 + (lane >> 4) * 8];
#pragma unroll
      for (int n = 0; n < 4; ++n)
        bb[n] = *(const bf16x8*)&WnT[(size_t)(out0 + n * 16 + (lane & 15)) * 192 + kk * 32 + (lane >> 4) * 8];
#pragma unroll
      for (int m = 0; m < MFR; ++m)
#pragma unroll
        for (int n = 0; n < 4; ++n)
          acc2[m][n] = __builtin_amdgcn_mfma_f32_16x16x32_bf16(a[m], bb[n], acc2[m][n], 0, 0, 0);
    }
  }
#pragma unroll
  for (int m = 0; m < MFR; ++m) {
    float ax4[4];
    if (RK1) {
      float4 v = *(const float4*)&axv[((size_t)b_eff << 10) + row0 + arow0 + m * 16 + ((lane >> 4) << 2)];
      ax4[0] = v.x; ax4[1] = v.y; ax4[2] = v.z; ax4[3] = v.w;
    }
#pragma unroll
    for (int n = 0; n < 4; ++n) {
      int cp = out0 + n * 16 + (lane & 15);
      int grow = arow0 + m * 16 + ((lane >> 4) << 2);
      size_t idx = (((size_t)b_eff << LOGC) + cp) * 1024 + row0 + grow;
      u16x4 zv = *(const u16x4*)&zT[idx];
      u16x4 hv = *(const u16x4*)&hT[idx];
      u16x4 pk;
#pragma unroll
      for (int j = 0; j < 4; ++j) {
        float g = acc2[m][n][j] + bias[cp];
        if (RK1) g += ax4[j] * wx[cp];
        float nv = tanhf(g);
        float z = bf2f(zv[j]), ho = bf2f(hv[j]);
        pk[j] = f2bf((1.f - z) * ho + z * nv);
      }
      *(u16x4*)&hT[idx] = pk;
    }
  }
}

// ---------------- fused AH1 = adj@h1 + zr1(t) + zr0(t+1) (device) -------------------
__device__ __forceinline__ void dev_ah1_zr(
    int bx, int by, char* lds,
    const u16* __restrict__ adjB, const u16* __restrict__ h1T,
    const u16* __restrict__ AH2, const u16* __restrict__ h2T,
    const u16* __restrict__ WzrT1, const float* __restrict__ bz1, const float* __restrict__ br1,
    const u16* __restrict__ WzrT0, const float* __restrict__ bz0, const float* __restrict__ br0,
    const float* __restrict__ AXt1, const float* __restrict__ wz0x, const float* __restrict__ wr0x,
    u16* __restrict__ AH1, u16* __restrict__ z1T, u16* __restrict__ rh1T,
    u16* __restrict__ z0T, u16* __restrict__ rh0T, int do_zr0) {
  int tid = threadIdx.x, w = tid >> 6, lane = tid & 63;
  int row0 = by * 64, col0 = bx * 128;
  int b0 = col0 >> 6;
  int wm = w >> 1, wn = w & 1;
  f32x4 acc[2][4] = {};
  for (int k0 = 0; k0 < 1024; k0 += 64) {
#pragma unroll
    for (int q = 0; q < 2; ++q) {
      int row = q * 32 + w * 8 + (lane >> 3);
      gload16(adjB + (size_t)(row0 + row) * 1024 + k0 + (lane & 7) * 8,
              lds + q * 4096 + w * 1024);
    }
#pragma unroll
    for (int q = 0; q < 4; ++q) {
      int row = q * 32 + w * 8 + (lane >> 3);
      gload16(h1T + (size_t)(col0 + row) * 1024 + k0 + (lane & 7) * 8,
              lds + 8192 + q * 4096 + w * 1024);
    }
    __syncthreads();
#pragma unroll
    for (int kk = 0; kk < 2; ++kk) {
      bf16x8 a[2], bb[4];
#pragma unroll
      for (int m = 0; m < 2; ++m)
        a[m] = *(const bf16x8*)(lds + (wm * 32 + m * 16 + (lane & 15)) * 128 + kk * 64 + (lane >> 4) * 16);
#pragma unroll
      for (int n = 0; n < 4; ++n)
        bb[n] = *(const bf16x8*)(lds + 8192 + (wn * 64 + n * 16 + (lane & 15)) * 128 + kk * 64 + (lane >> 4) * 16);
#pragma unroll
      for (int m = 0; m < 2; ++m)
#pragma unroll
        for (int n = 0; n < 4; ++n)
          acc[m][n] = __builtin_amdgcn_mfma_f32_16x16x32_bf16(a[m], bb[n], acc[m][n], 0, 0, 0);
    }
    __syncthreads();
  }
  u16* ANt = (u16*)lds;
#pragma unroll
  for (int m = 0; m < 2; ++m)
#pragma unroll
    for (int n = 0; n < 4; ++n) {
      int col = wn * 64 + n * 16 + (lane & 15);
      int bl = col >> 6, c = col & 63;
      int rl = wm * 32 + m * 16 + ((lane >> 4) << 2);
#pragma unroll
      for (int j = 0; j < 4; ++j) {
        u16 v = f2bf(acc[m][n][j]);
        AH1[(((size_t)(b0 + bl) << 10) + row0 + rl + j) * 64 + c] = v;
        ANt[(bl * 64 + rl + j) * 72 + c] = v;
      }
    }
  __syncthreads();
  int b = b0 + wm;
#pragma unroll
  for (int hz = 0; hz < 2; ++hz) {
    f32x4 g1[4][4] = {};
#pragma unroll
    for (int kk = 0; kk < 2; ++kk) {
      bf16x8 a[4], bb[4];
#pragma unroll
      for (int m = 0; m < 4; ++m)
        a[m] = *(const bf16x8*)&ANt[(wm * 64 + m * 16 + (lane & 15)) * 72 + kk * 32 + (lane >> 4) * 8];
#pragma unroll
      for (int n = 0; n < 4; ++n) {
        int out = hz * 128 + wn * 64 + n * 16 + (lane & 15);
        bb[n] = *(const bf16x8*)&WzrT1[(size_t)out * 192 + kk * 32 + (lane >> 4) * 8];
      }
#pragma unroll
      for (int m = 0; m < 4; ++m)
#pragma unroll
        for (int n = 0; n < 4; ++n)
          g1[m][n] = __builtin_amdgcn_mfma_f32_16x16x32_bf16(a[m], bb[n], g1[m][n], 0, 0, 0);
    }
#pragma unroll
    for (int kk = 0; kk < 4; ++kk) {
      bf16x8 a[4], bb[4];
#pragma unroll
      for (int m = 0; m < 4; ++m) {
        int gn = row0 + m * 16 + (lane & 15);
        a[m] = *(const bf16x8*)&AH2[(((size_t)b << 10) + gn) * 128 + kk * 32 + (lane >> 4) * 8];
      }
#pragma unroll
      for (int n = 0; n < 4; ++n) {
        int out = hz * 128 + wn * 64 + n * 16 + (lane & 15);
        bb[n] = *(const bf16x8*)&WzrT1[(size_t)out * 192 + 64 + kk * 32 + (lane >> 4) * 8];
      }
#pragma unroll
      for (int m = 0; m < 4; ++m)
#pragma unroll
        for (int n = 0; n < 4; ++n)
          g1[m][n] = __builtin_amdgcn_mfma_f32_16x16x32_bf16(a[m], bb[n], g1[m][n], 0, 0, 0);
    }
#pragma unroll
    for (int m = 0; m < 4; ++m)
#pragma unroll
      for (int n = 0; n < 4; ++n) {
        int outq = hz * 128 + wn * 64 + n * 16 + (lane & 15);
        bool iz = outq < 128;
        int c = iz ? outq : outq - 128;
        int gr = m * 16 + ((lane >> 4) << 2);
        size_t idx = (((size_t)b * 128 + c) << 10) + row0 + gr;
        u16x4 hv;
        if (!iz) hv = *(const u16x4*)&h2T[idx];
        u16x4 pk;
#pragma unroll
        for (int j = 0; j < 4; ++j) {
          float g = g1[m][n][j] + (iz ? bz1 : br1)[c];
          float sg = sigm(g);
          pk[j] = iz ? f2bf(sg) : f2bf(sg * bf2f(hv[j]));
        }
        *(u16x4*)&(iz ? z1T : rh1T)[idx] = pk;
      }
  }
  if (do_zr0) {
    f32x4 g0[4][4] = {};
#pragma unroll
    for (int kk = 0; kk < 2; ++kk) {
      bf16x8 a[4], bb[4];
#pragma unroll
      for (int m = 0; m < 4; ++m)
        a[m] = *(const bf16x8*)&ANt[(wm * 64 + m * 16 + (lane & 15)) * 72 + kk * 32 + (lane >> 4) * 8];
#pragma unroll
      for (int n = 0; n < 4; ++n) {
        int out = wn * 64 + n * 16 + (lane & 15);
        bb[n] = *(const bf16x8*)&WzrT0[(size_t)out * 64 + kk * 32 + (lane >> 4) * 8];
      }
#pragma unroll
      for (int m = 0; m < 4; ++m)
#pragma unroll
        for (int n = 0; n < 4; ++n)
          g0[m][n] = __builtin_amdgcn_mfma_f32_16x16x32_bf16(a[m], bb[n], g0[m][n], 0, 0, 0);
    }
#pragma unroll
    for (int m = 0; m < 4; ++m) {
      int gr0 = m * 16 + ((lane >> 4) << 2);
      float4 av = *(const float4*)&AXt1[((size_t)b << 10) + row0 + gr0];
      float ax4[4] = {av.x, av.y, av.z, av.w};
#pragma unroll
      for (int n = 0; n < 4; ++n) {
        int out = wn * 64 + n * 16 + (lane & 15);
        bool iz = out < 64;
        int c = out & 63;
        size_t idx = (((size_t)b * 64 + c) << 10) + row0 + gr0;
        u16x4 hv;
        if (!iz) hv = *(const u16x4*)&h1T[idx];
        u16x4 pk;
#pragma unroll
        for (int j = 0; j < 4; ++j) {
          float g = g0[m][n][j] + (iz ? bz0 : br0)[c] + ax4[j] * (iz ? wz0x : wr0x)[c];
          float sg = sigm(g);
          pk[j] = iz ? f2bf(sg) : f2bf(sg * bf2f(hv[j]));
        }
        *(u16x4*)&(iz ? z0T : rh0T)[idx] = pk;
      }
    }
  }
}

// ---------------- persistent cooperative loop: 16 steps x 3 phases ------------------
// grid 1024 blocks x 256 threads; LDS 34816 -> 4 blocks/CU -> exactly co-resident.
__global__ __launch_bounds__(256, 4) void loop_coop(
    const u16* adjB, u16* h1T, u16* h2T,
    const u16* WzrT0, const u16* WnT0, const u16* WzrT1, const u16* WnT1,
    const float* bz0, const float* br0, const float* bn0,
    const float* bz1, const float* br1, const float* bn1,
    const float* Wz0, const float* Wr0, const float* Wn0,
    const float* AXv,
    u16* AH1, u16* AH2, u16* z0T, u16* z1T, u16* rh0T, u16* rh1T) {
  __shared__ __align__(16) char lds[34816];
  cg::grid_group grid = cg::this_grid();
  int bid = blockIdx.x;
  for (int t = 0; t < T; ++t) {
    const float* AXn = AXv + (size_t)((t + 1 < T) ? t + 1 : t) * 65536;
    int do0 = (t + 1 < T) ? 1 : 0;
    // phase 1: AH1 = adj@h1 ; zr1(t) ; zr0(t+1)   [512 work items]
    if (bid < 512)
      dev_ah1_zr(bid & 31, bid >> 5, lds, adjB, h1T, AH2, h2T, WzrT1, bz1, br1,
                 WzrT0, bz0, br0, AXn, Wz0, Wr0, AH1, z1T, rh1T, z0T, rh0T, do0);
    grid.sync();
    // phase 2: layer-1 GRU update                  [512 work items]
    if (bid < 512)
      dev_adj_ngate<128, 0, 4>(bid & 63, bid >> 6, lds, adjB, rh1T, WnT1, bn1,
                               nullptr, nullptr, AH1, z1T, h2T);
    grid.sync();
    // phase 3: AH2(t) || layer-0 update of t+1     [1024 work items]
    if (t + 1 < T) {
      if (bid < 512)
        dev_adj_mfma<0, 7, 4>(bid & 63, bid >> 6, lds, adjB, h2T, AH2);
      else
        dev_adj_ngate<64, 1, 2>((bid - 512) & 31, (bid - 512) >> 5, lds, adjB,
                                rh0T, WnT0, bn0, AXn, Wn0, nullptr, z0T, h1T);
      grid.sync();
    }
  }
}

// ---------------- transpose final states: X[b][n*192+c] bf16 ------------------------
__global__ __launch_bounds__(256) void transpose_x(const u16* __restrict__ h1T,
                                                   const u16* __restrict__ h2T,
                                                   u16* __restrict__ X) {
  int b = blockIdx.x;
  int n0 = blockIdx.y * 128;
  __shared__ u16 tile[192][136];
  int tid = threadIdx.x;
#pragma unroll
  for (int i = 0; i < 12; ++i) {
    int id = tid + i * 256;
    int c = id >> 4, g = id & 15;
    u16x8 v;
    if (c < 64) v = *(const u16x8*)&h1T[(((size_t)b << 6) + c) * 1024 + n0 + g * 8];
    else        v = *(const u16x8*)&h2T[(((size_t)b << 7) + (c - 64)) * 1024 + n0 + g * 8];
    *(u16x8*)&tile[c][g * 8] = v;
  }
  __syncthreads();
#pragma unroll
  for (int i = 0; i < 12; ++i) {
    int id = tid + i * 256;
    int n = id / 24, g = id % 24;
    u16x8 v;
#pragma unroll
    for (int j = 0; j < 8; ++j) v[j] = tile[g * 8 + j][n];
    *(u16x8*)&X[(size_t)b * 196608 + (size_t)(n0 + n) * 192 + g * 8] = v;
  }
}

// ---------------- dense head: MFMA, float4 W loads + reg prefetch -------------------
__global__ __launch_bounds__(256) void dense_mfma4(const u16* __restrict__ X,
                                                   const float* __restrict__ Wmu,
                                                   const float* __restrict__ Wlv,
                                                   float* __restrict__ P) {
  __shared__ __align__(16) char lds[8192 + 128 * 70 * 2];
  u16* Bs = (u16*)(lds + 8192);
  int tid = threadIdx.x, w = tid >> 6, lane = tid & 63;
  int o0 = blockIdx.x * 128;
  int ch = blockIdx.y, mat = blockIdx.z;
  const float* W = mat ? Wlv : Wmu;
  int kb = ch * DKCHUNK;
  int oq = (tid & 31) * 4;
  int kq = (tid >> 5) * 8;
  f32x4 acc[4][2] = {};
  float4 wv[8];
  {
    const float* wp = W + (size_t)(kb + kq) * 256 + o0 + oq;
#pragma unroll
    for (int p = 0; p < 8; ++p) wv[p] = *(const float4*)(wp + (size_t)p * 256);
  }
  for (int s = 0; s < DKCHUNK / 64; ++s) {
    int kg = kb + s * 64;
#pragma unroll
    for (int q = 0; q < 2; ++q) {
      int row = q * 32 + w * 8 + (lane >> 3);
      gload16(X + (size_t)row * 196608 + kg + (lane & 7) * 8,
              lds + q * 4096 + w * 1024);
    }
#pragma unroll
    for (int j = 0; j < 4; ++j) {
      u16x8 pk;
#pragma unroll
      for (int p = 0; p < 8; ++p) pk[p] = f2bf(wv[p][j]);
      *(u16x8*)&Bs[(oq + j) * 70 + kq] = pk;
    }
    __syncthreads();
    if (s + 1 < DKCHUNK / 64) {
      const float* wp = W + (size_t)(kg + 64 + kq) * 256 + o0 + oq;
#pragma unroll
      for (int p = 0; p < 8; ++p) wv[p] = *(const float4*)(wp + (size_t)p * 256);
    }
#pragma unroll
    for (int kk = 0; kk < 2; ++kk) {
      bf16x8 a[4], bb[2];
#pragma unroll
      for (int m = 0; m < 4; ++m)
        a[m] = *(const bf16x8*)(lds + (m * 16 + (lane & 15)) * 128 + kk * 64 + (lane >> 4) * 16);
#pragma unroll
      for (int n = 0; n < 2; ++n) {
        int o = w * 32 + n * 16 + (lane & 15);
        bb[n] = *(const bf16x8*)&Bs[o * 70 + kk * 32 + (lane >> 4) * 8];
      }
#pragma unroll
      for (int m = 0; m < 4; ++m)
#pragma unroll
        for (int n = 0; n < 2; ++n)
          acc[m][n] = __builtin_amdgcn_mfma_f32_16x16x32_bf16(a[m], bb[n], acc[m][n], 0, 0, 0);
    }
    __syncthreads();
  }
#pragma unroll
  for (int m = 0; m < 4; ++m)
#pragma unroll
    for (int n = 0; n < 2; ++n) {
      int o = o0 + w * 32 + n * 16 + (lane & 15);
#pragma unroll
      for (int j = 0; j < 4; ++j) {
        int row = m * 16 + ((lane >> 4) << 2) + j;
        P[(((size_t)mat * DKCH + ch) * 64 + row) * 256 + o] = acc[m][n][j];
      }
    }
}

// ---------------- threefry / eps ----------------------------------------------------
__device__ __forceinline__ unsigned rotl32(unsigned v, int s) {
  return (v << s) | (v >> (32 - s));
}
__device__ void threefry(unsigned k0, unsigned k1, unsigned x0, unsigned x1,
                         unsigned& o0, unsigned& o1) {
  unsigned ks2 = k0 ^ k1 ^ 0x1BD11BDAu;
  unsigned a = x0 + k0, b = x1 + k1;
#define TF_RND(rot) { a += b; b = rotl32(b, rot); b ^= a; }
  TF_RND(13) TF_RND(15) TF_RND(26) TF_RND(6)
  a += k1; b += ks2 + 1u;
  TF_RND(17) TF_RND(29) TF_RND(16) TF_RND(24)
  a += ks2; b += k0 + 2u;
  TF_RND(13) TF_RND(15) TF_RND(26) TF_RND(6)
  a += k0; b += k1 + 3u;
  TF_RND(17) TF_RND(29) TF_RND(16) TF_RND(24)
  a += k1; b += ks2 + 4u;
  TF_RND(13) TF_RND(15) TF_RND(26) TF_RND(6)
  a += ks2; b += k0 + 5u;
#undef TF_RND
  o0 = a; o1 = b;
}

__device__ float u32_to_normal(unsigned bits) {
  unsigned fb = (bits >> 9) | 0x3F800000u;
  float f = __uint_as_float(fb) - 1.0f;
  const float lo = -0.99999994f;
  float u = f * 2.0f + lo;
  u = fmaxf(lo, u);
  float w = -log1pf(-u * u);
  float p;
  if (w < 5.0f) {
    w -= 2.5f;
    p = 2.81022636e-08f;
    p = fmaf(p, w, 3.43273939e-07f);
    p = fmaf(p, w, -3.5233877e-06f);
    p = fmaf(p, w, -4.39150654e-06f);
    p = fmaf(p, w, 0.00021858087f);
    p = fmaf(p, w, -0.00125372503f);
    p = fmaf(p, w, -0.00417768164f);
    p = fmaf(p, w, 0.246640727f);
    p = fmaf(p, w, 1.50140941f);
  } else {
    w = sqrtf(w) - 3.0f;
    p = -0.000200214257f;
    p = fmaf(p, w, 0.000100950558f);
    p = fmaf(p, w, 0.00134934322f);
    p = fmaf(p, w, -0.00367342844f);
    p = fmaf(p, w, 0.00573950773f);
    p = fmaf(p, w, -0.0076224613f);
    p = fmaf(p, w, 0.00943887047f);
    p = fmaf(p, w, 1.00167406f);
    p = fmaf(p, w, 2.83297682f);
  }
  return 1.41421354f * (p * u);
}

__global__ __launch_bounds__(256) void eps_kernel(float* __restrict__ eps) {
  int b = blockIdx.x;
  int o = threadIdx.x;
  unsigned k0, k1;
  threefry(0u, 0u, 0u, 1234u, k0, k1);
  float s = 0.f;
  for (int smp = 0; smp < 50; ++smp) {
    unsigned idx = ((unsigned)smp * 64u + (unsigned)b) * 256u + (unsigned)o;
    unsigned o0, o1, bits;
#if EPS_MODE == 0
    threefry(k0, k1, 0u, idx, o0, o1);
    bits = o0 ^ o1;
#else
    unsigned pp = idx % 409600u, half = idx / 409600u;
    threefry(k0, k1, pp, pp + 409600u, o0, o1);
    bits = half ? o1 : o0;
#endif
    s += u32_to_normal(bits);
  }
  eps[b * 256 + o] = s / 50.0f;
}

// ---------------- final reduce + heads + reparam ------------------------------------
__global__ __launch_bounds__(256) void final_kernel(const float* __restrict__ P,
                                                    const float* __restrict__ bmu,
                                                    const float* __restrict__ blv,
                                                    const float* __restrict__ eps,
                                                    float* __restrict__ out) {
  int b = blockIdx.x, o = threadIdx.x;
  float smu = 0.f, slv = 0.f;
  for (int ch = 0; ch < DKCH; ++ch) {
    smu += P[(((size_t)0 * DKCH + ch) * 64 + b) * 256 + o];
    slv += P[(((size_t)1 * DKCH + ch) * 64 + b) * 256 + o];
  }
  float mu = sigm(smu + bmu[o]);
  float lv = sigm(slv + blv[o]);
  float z = mu + eps[b * 256 + o] * expf(0.5f * lv);
  out[b * 256 + o] = z;
  out[16384 + b * 256 + o] = mu;
  out[32768 + b * 256 + o] = lv;
}

// ------------------------------------------------------------------------------------
extern "C" void kernel_launch(void* const* d_in, const int* in_sizes, int n_in,
                              void* d_out, int out_size, void* d_ws, size_t ws_size,
                              hipStream_t stream) {
  (void)in_sizes; (void)n_in; (void)out_size; (void)ws_size;
  const float* xs  = (const float*)d_in[0];
  const float* adj = (const float*)d_in[1];
  const float* Wz0 = (const float*)d_in[2];  const float* bz0 = (const float*)d_in[3];
  const float* Wr0 = (const float*)d_in[4];  const float* br0 = (const float*)d_in[5];
  const float* Wn0 = (const float*)d_in[6];  const float* bn0 = (const float*)d_in[7];
  const float* Wz1 = (const float*)d_in[8];  const float* bz1 = (const float*)d_in[9];
  const float* Wr1 = (const float*)d_in[10]; const float* br1 = (const float*)d_in[11];
  const float* Wn1 = (const float*)d_in[12]; const float* bn1 = (const float*)d_in[13];
  const float* Wmu = (const float*)d_in[14]; const float* bmu = (const float*)d_in[15];
  const float* Wlv = (const float*)d_in[16]; const float* blv = (const float*)d_in[17];

  float* ws = (float*)d_ws;
  u16*  adjB  = (u16*)(ws);                  // 0.0  (0.5)
  u16*  xsB   = (u16*)(ws + MF / 2);         // 0.5  (0.5)
  float* AXv  = ws + 1 * MF;                 // 1.0  (1.0)
  u16*  h1T   = (u16*)(ws + 2 * MF);         // 2.0  (2.0)
  u16*  h2T   = (u16*)(ws + 4 * MF);         // 4.0  (4.0)
  u16*  z0T   = (u16*)(ws + 8 * MF);         // 8.0  (2.0)
  u16*  z1T   = (u16*)(ws + 10 * MF);        // 10.0 (4.0)
  u16*  rh0T  = (u16*)(ws + 14 * MF);        // 14.0 (2.0)
  u16*  rh1T  = (u16*)(ws + 16 * MF);        // 16.0 (4.0)
  u16*  AH1   = (u16*)(ws + 20 * MF);        // 20.0 (2.0)
  u16*  AH2   = (u16*)(ws + 22 * MF);        // 22.0 (4.0)
  u16*  WTb   = (u16*)(ws + 26 * MF);        // 26.0 (0.125)
  // post-loop aliases:
  u16*  X     = (u16*)(ws + 8 * MF);         // 8.0  (6.0)
  float* P    = ws + 16 * MF;                // 16.0 (16.78) dense partials (DKCH=512)
  float* EPS  = ws + 33 * MF;                // 33.0

  u16* WzrT0 = WTb;
  u16* WnT0  = WTb + 8192;
  u16* WzrT1 = WTb + 12288;
  u16* WnT1  = WTb + 61440;

  // zero only the buffers read before first write: h2T and AH2
  hipMemsetAsync(ws + 4 * MF, 0, 4 * MF * sizeof(float), stream);
  hipMemsetAsync(ws + 22 * MF, 0, 4 * MF * sizeof(float), stream);

  cast_bf16<<<1024, 256, 0, stream>>>(adj, adjB, 1 << 20);
  cast_bf16<<<1024, 256, 0, stream>>>(xs, xsB, 1 << 20);
  prep_wt<<<dim3(192, 4), 256, 0, stream>>>(Wz0, Wr0, Wn0, Wz1, Wr1, Wn1,
                                            WzrT0, WnT0, WzrT1, WnT1);

  // AX[t][b][n] for all t
  adj_mfma<1, 0, 4><<<dim3(8, 8), 256, 0, stream>>>(adjB, xsB, AXv);

  // prologue: t=0 layer-0 closed form (adj@(r*h)=0 since h1=0)
  init0<<<dim3(64, 4), 256, 0, stream>>>(AXv, Wz0, bz0, Wn0, bn0, h1T);

  // persistent cooperative loop (16 steps x 3 phases)
  {
    void* cargs[] = {
        (void*)&adjB, (void*)&h1T, (void*)&h2T,
        (void*)&WzrT0, (void*)&WnT0, (void*)&WzrT1, (void*)&WnT1,
        (void*)&bz0, (void*)&br0, (void*)&bn0,
        (void*)&bz1, (void*)&br1, (void*)&bn1,
        (void*)&Wz0, (void*)&Wr0, (void*)&Wn0,
        (void*)&AXv,
        (void*)&AH1, (void*)&AH2, (void*)&z0T, (void*)&z1T,
        (void*)&rh0T, (void*)&rh1T};
    hipLaunchCooperativeKernel((void*)loop_coop, dim3(1024), dim3(256), cargs, 0,
                               stream);
  }

  // dense heads
  transpose_x<<<dim3(64, 8), 256, 0, stream>>>(h1T, h2T, X);
  dense_mfma4<<<dim3(2, DKCH, 2), 256, 0, stream>>>(X, Wmu, Wlv, P);
  eps_kernel<<<64, 256, 0, stream>>>(EPS);
  final_kernel<<<64, 256, 0, stream>>>(P, bmu, blv, EPS, (float*)d_out);
}

// Round 15
// 2715.392 us; speedup vs baseline: 3.7822x; 3.7822x over previous
//
#include <hip/hip_runtime.h>
#include <math.h>

#define EPS_MODE 0

typedef unsigned short u16;
typedef short bf16x8 __attribute__((ext_vector_type(8)));
typedef float f32x4 __attribute__((ext_vector_type(4)));
typedef u16 u16x4 __attribute__((ext_vector_type(4)));
typedef u16 u16x8 __attribute__((ext_vector_type(8)));

static constexpr int T = 16;
static constexpr size_t MF = 1u << 20;
static constexpr int DKCH = 512;                // dense split-K chunks
static constexpr int DKCHUNK = 196608 / DKCH;   // 384

__device__ __forceinline__ u16 f2bf(float f) {
  unsigned u = __float_as_uint(f);
  unsigned r = (u + 0x7fffu + ((u >> 16) & 1u)) >> 16;
  return (u16)r;
}
__device__ __forceinline__ float bf2f(u16 h) {
  return __uint_as_float(((unsigned)h) << 16);
}
__device__ __forceinline__ void gload16(const void* g, void* l) {
  __builtin_amdgcn_global_load_lds(
      (const __attribute__((address_space(1))) void*)g,
      (__attribute__((address_space(3))) void*)l, 16, 0, 0);
}
__device__ __forceinline__ float sigm(float x) { return 1.f / (1.f + expf(-x)); }

// ---------------- casts -------------------------------------------------------------
__global__ __launch_bounds__(256) void cast_bf16(const float* __restrict__ in,
                                                 u16* __restrict__ out, int n) {
  int i = (blockIdx.x * 256 + threadIdx.x) * 4;
  if (i < n) {
    float4 v = *reinterpret_cast<const float4*>(&in[i]);
    out[i + 0] = f2bf(v.x); out[i + 1] = f2bf(v.y);
    out[i + 2] = f2bf(v.z); out[i + 3] = f2bf(v.w);
  }
}

// ---------------- W transpose+cast: WT[col][k] --------------------------------------
__global__ __launch_bounds__(256) void prep_wt(const float* __restrict__ Wz0, const float* __restrict__ Wr0,
                                               const float* __restrict__ Wn0, const float* __restrict__ Wz1,
                                               const float* __restrict__ Wr1, const float* __restrict__ Wn1,
                                               u16* __restrict__ WzrT0, u16* __restrict__ WnT0,
                                               u16* __restrict__ WzrT1, u16* __restrict__ WnT1) {
  int seg = blockIdx.y;
  int idx = blockIdx.x * 256 + threadIdx.x;
  if (seg == 0) {
    if (idx < 128 * 64) {
      int j = idx >> 6, k = idx & 63;
      float v = (j < 64) ? Wz0[(k + 1) * 64 + j] : Wr0[(k + 1) * 64 + (j - 64)];
      WzrT0[idx] = f2bf(v);
    }
  } else if (seg == 1) {
    if (idx < 64 * 64) {
      int j = idx >> 6, k = idx & 63;
      WnT0[idx] = f2bf(Wn0[(k + 1) * 64 + j]);
    }
  } else if (seg == 2) {
    if (idx < 256 * 192) {
      int j = idx / 192, k = idx % 192;
      float v = (j < 128) ? Wz1[k * 128 + j] : Wr1[k * 128 + (j - 128)];
      WzrT1[idx] = f2bf(v);
    }
  } else {
    if (idx < 128 * 192) {
      int j = idx / 192, k = idx % 192;
      WnT1[idx] = f2bf(Wn1[k * 128 + j]);
    }
  }
}

// ---------------- t=0 layer-0 closed form: h1 = sigm(ax*wz+bz)*tanh(ax*wn+bn) -------
__global__ __launch_bounds__(256) void init0(const float* __restrict__ AXv,
                                             const float* __restrict__ Wz0,
                                             const float* __restrict__ bz0,
                                             const float* __restrict__ Wn0,
                                             const float* __restrict__ bn0,
                                             u16* __restrict__ h1T) {
  int b = blockIdx.x, n0 = blockIdx.y * 256;
  __shared__ float axs[256];
  int tid = threadIdx.x;
  if (tid < 64)
    *(float4*)&axs[tid * 4] = *(const float4*)&AXv[((size_t)b << 10) + n0 + tid * 4];
  __syncthreads();
  int cb = tid >> 6, nl = (tid & 63) * 4;
  for (int c0 = 0; c0 < 64; c0 += 4) {
    int c = c0 + cb;
    float wz = Wz0[c], bz = bz0[c], wn = Wn0[c], bn = bn0[c];
    u16x4 pk;
#pragma unroll
    for (int j = 0; j < 4; ++j) {
      float ax = axs[nl + j];
      float z = sigm(fmaf(ax, wz, bz));
      pk[j] = f2bf(z * tanhf(fmaf(ax, wn, bn)));
    }
    *(u16x4*)&h1T[((((size_t)b << 6) + c) << 10) + n0 + nl] = pk;
  }
}

// ---------------- adjacency MFMA GEMM (device) --------------------------------------
template <int EPI, int LOGC, int MFR>
__device__ __forceinline__ void dev_adj_mfma(int bx, int by, char* lds,
                                             const u16* __restrict__ A,
                                             const u16* __restrict__ BT,
                                             void* __restrict__ OUT) {
  constexpr int MT = MFR * 32;
  int tid = threadIdx.x;
  int w = tid >> 6, lane = tid & 63;
  int row0 = by * MT, col0 = bx * 128;
  int wm = w >> 1, wn = w & 1;
  f32x4 acc[MFR][4] = {};
  for (int k0 = 0; k0 < 1024; k0 += 64) {
#pragma unroll
    for (int q = 0; q < MFR; ++q) {
      int row = q * 32 + w * 8 + (lane >> 3);
      gload16(A + (size_t)(row0 + row) * 1024 + k0 + (lane & 7) * 8,
              lds + q * 4096 + w * 1024);
    }
#pragma unroll
    for (int q = 0; q < 4; ++q) {
      int row = q * 32 + w * 8 + (lane >> 3);
      gload16(BT + (size_t)(col0 + row) * 1024 + k0 + (lane & 7) * 8,
              lds + MFR * 4096 + q * 4096 + w * 1024);
    }
    __syncthreads();
#pragma unroll
    for (int kk = 0; kk < 2; ++kk) {
      bf16x8 a[MFR], bb[4];
#pragma unroll
      for (int m = 0; m < MFR; ++m)
        a[m] = *(const bf16x8*)(lds + (wm * (MFR * 16) + m * 16 + (lane & 15)) * 128 + kk * 64 + (lane >> 4) * 16);
#pragma unroll
      for (int n = 0; n < 4; ++n)
        bb[n] = *(const bf16x8*)(lds + MFR * 4096 + (wn * 64 + n * 16 + (lane & 15)) * 128 + kk * 64 + (lane >> 4) * 16);
#pragma unroll
      for (int m = 0; m < MFR; ++m)
#pragma unroll
        for (int n = 0; n < 4; ++n)
          acc[m][n] = __builtin_amdgcn_mfma_f32_16x16x32_bf16(a[m], bb[n], acc[m][n], 0, 0, 0);
    }
    __syncthreads();
  }
  if (EPI == 1) {
    float* O = (float*)OUT;
#pragma unroll
    for (int m = 0; m < MFR; ++m)
#pragma unroll
      for (int n = 0; n < 4; ++n) {
        int col = col0 + wn * 64 + n * 16 + (lane & 15);
        int t = col >> 6, bbx = col & 63;
        int row = row0 + wm * (MFR * 16) + m * 16 + ((lane >> 4) << 2);
        *(float4*)&O[((size_t)t << 16) + ((size_t)bbx << 10) + row] = *(float4*)&acc[m][n];
      }
  } else {
    u16* O = (u16*)OUT;
    constexpr int C = 1 << LOGC;
#pragma unroll
    for (int m = 0; m < MFR; ++m)
#pragma unroll
      for (int n = 0; n < 4; ++n) {
        int col = col0 + wn * 64 + n * 16 + (lane & 15);
        int bbx = col >> LOGC, c = col & (C - 1);
#pragma unroll
        for (int j = 0; j < 4; ++j) {
          int row = row0 + wm * (MFR * 16) + m * 16 + ((lane >> 4) << 2) + j;
          O[(((size_t)bbx << 10) + row) * C + c] = f2bf(acc[m][n][j]);
        }
      }
  }
}

template <int EPI, int LOGC, int MFR>
__global__ __launch_bounds__(256) void adj_mfma(const u16* __restrict__ A,
                                                const u16* __restrict__ BT,
                                                void* __restrict__ OUT) {
  __shared__ __align__(16) char lds[(MFR + 4) * 4096];
  dev_adj_mfma<EPI, LOGC, MFR>(blockIdx.x, blockIdx.y, lds, A, BT, OUT);
}

// ---------------- fused adj@(r*h) + n-gate + GRU update (device) --------------------
template <int C, int RK1, int MFR>
__device__ __forceinline__ void dev_adj_ngate(
    int bx, int by, char* lds,
    const u16* __restrict__ A, const u16* __restrict__ BT,
    const u16* __restrict__ WnT, const float* __restrict__ bias,
    const float* __restrict__ axv, const float* __restrict__ wx,
    const u16* __restrict__ AH1, const u16* __restrict__ zT,
    u16* __restrict__ hT) {
  constexpr int LOGC = (C == 64) ? 6 : 7;
  constexpr int KW = (C == 64) ? 64 : 192;
  constexpr int KKAN = C / 32;
  constexpr int MT = MFR * 32;
  int tid = threadIdx.x;
  int w = tid >> 6, lane = tid & 63;
  int row0 = by * MT, col0 = bx * 128;
  int wm = w >> 1, wn = w & 1;
  f32x4 acc[MFR][4] = {};
  for (int k0 = 0; k0 < 1024; k0 += 64) {
#pragma unroll
    for (int q = 0; q < MFR; ++q) {
      int row = q * 32 + w * 8 + (lane >> 3);
      gload16(A + (size_t)(row0 + row) * 1024 + k0 + (lane & 7) * 8,
              lds + q * 4096 + w * 1024);
    }
#pragma unroll
    for (int q = 0; q < 4; ++q) {
      int row = q * 32 + w * 8 + (lane >> 3);
      gload16(BT + (size_t)(col0 + row) * 1024 + k0 + (lane & 7) * 8,
              lds + MFR * 4096 + q * 4096 + w * 1024);
    }
    __syncthreads();
#pragma unroll
    for (int kk = 0; kk < 2; ++kk) {
      bf16x8 a[MFR], bb[4];
#pragma unroll
      for (int m = 0; m < MFR; ++m)
        a[m] = *(const bf16x8*)(lds + (wm * (MFR * 16) + m * 16 + (lane & 15)) * 128 + kk * 64 + (lane >> 4) * 16);
#pragma unroll
      for (int n = 0; n < 4; ++n)
        bb[n] = *(const bf16x8*)(lds + MFR * 4096 + (wn * 64 + n * 16 + (lane & 15)) * 128 + kk * 64 + (lane >> 4) * 16);
#pragma unroll
      for (int m = 0; m < MFR; ++m)
#pragma unroll
        for (int n = 0; n < 4; ++n)
          acc[m][n] = __builtin_amdgcn_mfma_f32_16x16x32_bf16(a[m], bb[n], acc[m][n], 0, 0, 0);
    }
    __syncthreads();
  }
  u16* ANt = (u16*)lds;
#pragma unroll
  for (int m = 0; m < MFR; ++m)
#pragma unroll
    for (int n = 0; n < 4; ++n) {
      int cl = wn * 64 + n * 16 + (lane & 15);
      int rl = wm * (MFR * 16) + m * 16 + ((lane >> 4) << 2);
#pragma unroll
      for (int j = 0; j < 4; ++j)
        ANt[(rl + j) * 136 + cl] = f2bf(acc[m][n][j]);
    }
  __syncthreads();
  int wrow = w >> 1, half = w & 1;
  int arow0 = wrow * (MFR * 16);
  int b0 = col0 >> LOGC;
  int out0 = (C == 64) ? 0 : half * 64;
  int kbase = (C == 64) ? half * 64 : 0;
  int b_eff = (C == 64) ? (b0 + half) : b0;
  constexpr int WOFF = (C == 64) ? 0 : 64;
  f32x4 acc2[MFR][4] = {};
#pragma unroll
  for (int kk = 0; kk < KKAN; ++kk) {
    bf16x8 a[MFR], bb[4];
    int ka = kbase + kk * 32 + (lane >> 4) * 8;
#pragma unroll
    for (int m = 0; m < MFR; ++m)
      a[m] = *(const bf16x8*)&ANt[(arow0 + m * 16 + (lane & 15)) * 136 + ka];
#pragma unroll
    for (int n = 0; n < 4; ++n)
      bb[n] = *(const bf16x8*)&WnT[(size_t)(out0 + n * 16 + (lane & 15)) * KW + WOFF + kk * 32 + (lane >> 4) * 8];
#pragma unroll
    for (int m = 0; m < MFR; ++m)
#pragma unroll
      for (int n = 0; n < 4; ++n)
        acc2[m][n] = __builtin_amdgcn_mfma_f32_16x16x32_bf16(a[m], bb[n], acc2[m][n], 0, 0, 0);
  }
  if (C == 128) {
#pragma unroll
    for (int kk = 0; kk < 2; ++kk) {
      bf16x8 a[MFR], bb[4];
#pragma unroll
      for (int m = 0; m < MFR; ++m)
        a[m] = *(const bf16x8*)&AH1[(((size_t)b0 << 10) + row0 + arow0 + m * 16 + (lane & 15)) * 64 + kk * 32 + (lane >> 4) * 8];
#pragma unroll
      for (int n = 0; n < 4; ++n)
        bb[n] = *(const bf16x8*)&WnT[(size_t)(out0 + n * 16 + (lane & 15)) * 192 + kk * 32 + (lane >> 4) * 8];
#pragma unroll
      for (int m = 0; m < MFR; ++m)
#pragma unroll
        for (int n = 0; n < 4; ++n)
          acc2[m][n] = __builtin_amdgcn_mfma_f32_16x16x32_bf16(a[m], bb[n], acc2[m][n], 0, 0, 0);
    }
  }
#pragma unroll
  for (int m = 0; m < MFR; ++m) {
    float ax4[4];
    if (RK1) {
      float4 v = *(const float4*)&axv[((size_t)b_eff << 10) + row0 + arow0 + m * 16 + ((lane >> 4) << 2)];
      ax4[0] = v.x; ax4[1] = v.y; ax4[2] = v.z; ax4[3] = v.w;
    }
#pragma unroll
    for (int n = 0; n < 4; ++n) {
      int cp = out0 + n * 16 + (lane & 15);
      int grow = arow0 + m * 16 + ((lane >> 4) << 2);
      size_t idx = (((size_t)b_eff << LOGC) + cp) * 1024 + row0 + grow;
      u16x4 zv = *(const u16x4*)&zT[idx];
      u16x4 hv = *(const u16x4*)&hT[idx];
      u16x4 pk;
#pragma unroll
      for (int j = 0; j < 4; ++j) {
        float g = acc2[m][n][j] + bias[cp];
        if (RK1) g += ax4[j] * wx[cp];
        float nv = tanhf(g);
        float z = bf2f(zv[j]), ho = bf2f(hv[j]);
        pk[j] = f2bf((1.f - z) * ho + z * nv);
      }
      *(u16x4*)&hT[idx] = pk;
    }
  }
}

template <int C, int RK1, int MFR>
__global__ __launch_bounds__(256) void adj_ngate(
    const u16* __restrict__ A, const u16* __restrict__ BT,
    const u16* __restrict__ WnT, const float* __restrict__ bias,
    const float* __restrict__ axv, const float* __restrict__ wx,
    const u16* __restrict__ AH1, const u16* __restrict__ zT,
    u16* __restrict__ hT) {
  constexpr int MT = MFR * 32;
  constexpr int STG = (MFR + 4) * 4096;
  constexpr int ANB = MT * 136 * 2;
  constexpr int LDSZ = STG > ANB ? STG : ANB;
  __shared__ __align__(16) char lds[LDSZ];
  dev_adj_ngate<C, RK1, MFR>(blockIdx.x, blockIdx.y, lds, A, BT, WnT, bias, axv, wx,
                             AH1, zT, hT);
}

// ---------------- combo: AH2(t) [512 blocks] + ngate64(t+1) [512 blocks] ------------
__global__ __launch_bounds__(256) void combo_tail(
    const u16* __restrict__ adjB, const u16* __restrict__ h2T, u16* __restrict__ AH2,
    const u16* __restrict__ rh0T, const u16* __restrict__ WnT0, const float* __restrict__ bn0,
    const float* __restrict__ AXt1, const float* __restrict__ Wn0,
    const u16* __restrict__ z0T, u16* __restrict__ h1T) {
  __shared__ __align__(16) char lds[32768];
  int bid = blockIdx.x;
  if (bid < 512) {
    dev_adj_mfma<0, 7, 4>(bid & 63, bid >> 6, lds, adjB, h2T, AH2);
  } else {
    int b2 = bid - 512;
    dev_adj_ngate<64, 1, 2>(b2 & 31, b2 >> 5, lds, adjB, rh0T, WnT0, bn0,
                            AXt1, Wn0, nullptr, z0T, h1T);
  }
}

// ---------------- fused AH1 = adj@h1 + zr1(t) + zr0(t+1) ----------------------------
__global__ __launch_bounds__(256) void ah1_zr(
    const u16* __restrict__ adjB, const u16* __restrict__ h1T,
    const u16* __restrict__ AH2, const u16* __restrict__ h2T,
    const u16* __restrict__ WzrT1, const float* __restrict__ bz1, const float* __restrict__ br1,
    const u16* __restrict__ WzrT0, const float* __restrict__ bz0, const float* __restrict__ br0,
    const float* __restrict__ AXt1, const float* __restrict__ wz0x, const float* __restrict__ wr0x,
    u16* __restrict__ AH1, u16* __restrict__ z1T, u16* __restrict__ rh1T,
    u16* __restrict__ z0T, u16* __restrict__ rh0T, int do_zr0) {
  __shared__ __align__(16) char lds[24576];
  int tid = threadIdx.x, w = tid >> 6, lane = tid & 63;
  int row0 = blockIdx.y * 64, col0 = blockIdx.x * 128;
  int b0 = col0 >> 6;
  int wm = w >> 1, wn = w & 1;
  f32x4 acc[2][4] = {};
  for (int k0 = 0; k0 < 1024; k0 += 64) {
#pragma unroll
    for (int q = 0; q < 2; ++q) {
      int row = q * 32 + w * 8 + (lane >> 3);
      gload16(adjB + (size_t)(row0 + row) * 1024 + k0 + (lane & 7) * 8,
              lds + q * 4096 + w * 1024);
    }
#pragma unroll
    for (int q = 0; q < 4; ++q) {
      int row = q * 32 + w * 8 + (lane >> 3);
      gload16(h1T + (size_t)(col0 + row) * 1024 + k0 + (lane & 7) * 8,
              lds + 8192 + q * 4096 + w * 1024);
    }
    __syncthreads();
#pragma unroll
    for (int kk = 0; kk < 2; ++kk) {
      bf16x8 a[2], bb[4];
#pragma unroll
      for (int m = 0; m < 2; ++m)
        a[m] = *(const bf16x8*)(lds + (wm * 32 + m * 16 + (lane & 15)) * 128 + kk * 64 + (lane >> 4) * 16);
#pragma unroll
      for (int n = 0; n < 4; ++n)
        bb[n] = *(const bf16x8*)(lds + 8192 + (wn * 64 + n * 16 + (lane & 15)) * 128 + kk * 64 + (lane >> 4) * 16);
#pragma unroll
      for (int m = 0; m < 2; ++m)
#pragma unroll
        for (int n = 0; n < 4; ++n)
          acc[m][n] = __builtin_amdgcn_mfma_f32_16x16x32_bf16(a[m], bb[n], acc[m][n], 0, 0, 0);
    }
    __syncthreads();
  }
  u16* ANt = (u16*)lds;
#pragma unroll
  for (int m = 0; m < 2; ++m)
#pragma unroll
    for (int n = 0; n < 4; ++n) {
      int col = wn * 64 + n * 16 + (lane & 15);
      int bl = col >> 6, c = col & 63;
      int rl = wm * 32 + m * 16 + ((lane >> 4) << 2);
#pragma unroll
      for (int j = 0; j < 4; ++j) {
        u16 v = f2bf(acc[m][n][j]);
        AH1[(((size_t)(b0 + bl) << 10) + row0 + rl + j) * 64 + c] = v;
        ANt[(bl * 64 + rl + j) * 72 + c] = v;
      }
    }
  __syncthreads();
  int b = b0 + wm;
#pragma unroll
  for (int hz = 0; hz < 2; ++hz) {
    f32x4 g1[4][4] = {};
#pragma unroll
    for (int kk = 0; kk < 2; ++kk) {
      bf16x8 a[4], bb[4];
#pragma unroll
      for (int m = 0; m < 4; ++m)
        a[m] = *(const bf16x8*)&ANt[(wm * 64 + m * 16 + (lane & 15)) * 72 + kk * 32 + (lane >> 4) * 8];
#pragma unroll
      for (int n = 0; n < 4; ++n) {
        int out = hz * 128 + wn * 64 + n * 16 + (lane & 15);
        bb[n] = *(const bf16x8*)&WzrT1[(size_t)out * 192 + kk * 32 + (lane >> 4) * 8];
      }
#pragma unroll
      for (int m = 0; m < 4; ++m)
#pragma unroll
        for (int n = 0; n < 4; ++n)
          g1[m][n] = __builtin_amdgcn_mfma_f32_16x16x32_bf16(a[m], bb[n], g1[m][n], 0, 0, 0);
    }
#pragma unroll
    for (int kk = 0; kk < 4; ++kk) {
      bf16x8 a[4], bb[4];
#pragma unroll
      for (int m = 0; m < 4; ++m) {
        int gn = row0 + m * 16 + (lane & 15);
        a[m] = *(const bf16x8*)&AH2[(((size_t)b << 10) + gn) * 128 + kk * 32 + (lane >> 4) * 8];
      }
#pragma unroll
      for (int n = 0; n < 4; ++n) {
        int out = hz * 128 + wn * 64 + n * 16 + (lane & 15);
        bb[n] = *(const bf16x8*)&WzrT1[(size_t)out * 192 + 64 + kk * 32 + (lane >> 4) * 8];
      }
#pragma unroll
      for (int m = 0; m < 4; ++m)
#pragma unroll
        for (int n = 0; n < 4; ++n)
          g1[m][n] = __builtin_amdgcn_mfma_f32_16x16x32_bf16(a[m], bb[n], g1[m][n], 0, 0, 0);
    }
#pragma unroll
    for (int m = 0; m < 4; ++m)
#pragma unroll
      for (int n = 0; n < 4; ++n) {
        int outq = hz * 128 + wn * 64 + n * 16 + (lane & 15);
        bool iz = outq < 128;
        int c = iz ? outq : outq - 128;
        int gr = m * 16 + ((lane >> 4) << 2);
        size_t idx = (((size_t)b * 128 + c) << 10) + row0 + gr;
        u16x4 hv;
        if (!iz) hv = *(const u16x4*)&h2T[idx];
        u16x4 pk;
#pragma unroll
        for (int j = 0; j < 4; ++j) {
          float g = g1[m][n][j] + (iz ? bz1 : br1)[c];
          float sg = sigm(g);
          pk[j] = iz ? f2bf(sg) : f2bf(sg * bf2f(hv[j]));
        }
        *(u16x4*)&(iz ? z1T : rh1T)[idx] = pk;
      }
  }
  if (do_zr0) {
    f32x4 g0[4][4] = {};
#pragma unroll
    for (int kk = 0; kk < 2; ++kk) {
      bf16x8 a[4], bb[4];
#pragma unroll
      for (int m = 0; m < 4; ++m)
        a[m] = *(const bf16x8*)&ANt[(wm * 64 + m * 16 + (lane & 15)) * 72 + kk * 32 + (lane >> 4) * 8];
#pragma unroll
      for (int n = 0; n < 4; ++n) {
        int out = wn * 64 + n * 16 + (lane & 15);
        bb[n] = *(const bf16x8*)&WzrT0[(size_t)out * 64 + kk * 32 + (lane >> 4) * 8];
      }
#pragma unroll
      for (int m = 0; m < 4; ++m)
#pragma unroll
        for (int n = 0; n < 4; ++n)
          g0[m][n] = __builtin_amdgcn_mfma_f32_16x16x32_bf16(a[m], bb[n], g0[m][n], 0, 0, 0);
    }
#pragma unroll
    for (int m = 0; m < 4; ++m) {
      int gr0 = m * 16 + ((lane >> 4) << 2);
      float4 av = *(const float4*)&AXt1[((size_t)b << 10) + row0 + gr0];
      float ax4[4] = {av.x, av.y, av.z, av.w};
#pragma unroll
      for (int n = 0; n < 4; ++n) {
        int out = wn * 64 + n * 16 + (lane & 15);
        bool iz = out < 64;
        int c = out & 63;
        size_t idx = (((size_t)b * 64 + c) << 10) + row0 + gr0;
        u16x4 hv;
        if (!iz) hv = *(const u16x4*)&h1T[idx];
        u16x4 pk;
#pragma unroll
        for (int j = 0; j < 4; ++j) {
          float g = g0[m][n][j] + (iz ? bz0 : br0)[c] + ax4[j] * (iz ? wz0x : wr0x)[c];
          float sg = sigm(g);
          pk[j] = iz ? f2bf(sg) : f2bf(sg * bf2f(hv[j]));
        }
        *(u16x4*)&(iz ? z0T : rh0T)[idx] = pk;
      }
    }
  }
}

// ---------------- transpose final states: X[b][n*192+c] bf16 ------------------------
__global__ __launch_bounds__(256) void transpose_x(const u16* __restrict__ h1T,
                                                   const u16* __restrict__ h2T,
                                                   u16* __restrict__ X) {
  int b = blockIdx.x;
  int n0 = blockIdx.y * 128;
  __shared__ u16 tile[192][136];
  int tid = threadIdx.x;
#pragma unroll
  for (int i = 0; i < 12; ++i) {
    int id = tid + i * 256;
    int c = id >> 4, g = id & 15;
    u16x8 v;
    if (c < 64) v = *(const u16x8*)&h1T[(((size_t)b << 6) + c) * 1024 + n0 + g * 8];
    else        v = *(const u16x8*)&h2T[(((size_t)b << 7) + (c - 64)) * 1024 + n0 + g * 8];
    *(u16x8*)&tile[c][g * 8] = v;
  }
  __syncthreads();
#pragma unroll
  for (int i = 0; i < 12; ++i) {
    int id = tid + i * 256;
    int n = id / 24, g = id % 24;
    u16x8 v;
#pragma unroll
    for (int j = 0; j < 8; ++j) v[j] = tile[g * 8 + j][n];
    *(u16x8*)&X[(size_t)b * 196608 + (size_t)(n0 + n) * 192 + g * 8] = v;
  }
}

// ---------------- dense head: MFMA, float4 W loads + reg prefetch -------------------
__global__ __launch_bounds__(256) void dense_mfma4(const u16* __restrict__ X,
                                                   const float* __restrict__ Wmu,
                                                   const float* __restrict__ Wlv,
                                                   float* __restrict__ P) {
  __shared__ __align__(16) char lds[8192 + 128 * 70 * 2];
  u16* Bs = (u16*)(lds + 8192);
  int tid = threadIdx.x, w = tid >> 6, lane = tid & 63;
  int o0 = blockIdx.x * 128;
  int ch = blockIdx.y, mat = blockIdx.z;
  const float* W = mat ? Wlv : Wmu;
  int kb = ch * DKCHUNK;
  int oq = (tid & 31) * 4;
  int kq = (tid >> 5) * 8;
  f32x4 acc[4][2] = {};
  float4 wv[8];
  {
    const float* wp = W + (size_t)(kb + kq) * 256 + o0 + oq;
#pragma unroll
    for (int p = 0; p < 8; ++p) wv[p] = *(const float4*)(wp + (size_t)p * 256);
  }
  for (int s = 0; s < DKCHUNK / 64; ++s) {
    int kg = kb + s * 64;
#pragma unroll
    for (int q = 0; q < 2; ++q) {
      int row = q * 32 + w * 8 + (lane >> 3);
      gload16(X + (size_t)row * 196608 + kg + (lane & 7) * 8,
              lds + q * 4096 + w * 1024);
    }
#pragma unroll
    for (int j = 0; j < 4; ++j) {
      u16x8 pk;
#pragma unroll
      for (int p = 0; p < 8; ++p) pk[p] = f2bf(wv[p][j]);
      *(u16x8*)&Bs[(oq + j) * 70 + kq] = pk;
    }
    __syncthreads();
    if (s + 1 < DKCHUNK / 64) {
      const float* wp = W + (size_t)(kg + 64 + kq) * 256 + o0 + oq;
#pragma unroll
      for (int p = 0; p < 8; ++p) wv[p] = *(const float4*)(wp + (size_t)p * 256);
    }
#pragma unroll
    for (int kk = 0; kk < 2; ++kk) {
      bf16x8 a[4], bb[2];
#pragma unroll
      for (int m = 0; m < 4; ++m)
        a[m] = *(const bf16x8*)(lds + (m * 16 + (lane & 15)) * 128 + kk * 64 + (lane >> 4) * 16);
#pragma unroll
      for (int n = 0; n < 2; ++n) {
        int o = w * 32 + n * 16 + (lane & 15);
        bb[n] = *(const bf16x8*)&Bs[o * 70 + kk * 32 + (lane >> 4) * 8];
      }
#pragma unroll
      for (int m = 0; m < 4; ++m)
#pragma unroll
        for (int n = 0; n < 2; ++n)
          acc[m][n] = __builtin_amdgcn_mfma_f32_16x16x32_bf16(a[m], bb[n], acc[m][n], 0, 0, 0);
    }
    __syncthreads();
  }
#pragma unroll
  for (int m = 0; m < 4; ++m)
#pragma unroll
    for (int n = 0; n < 2; ++n) {
      int o = o0 + w * 32 + n * 16 + (lane & 15);
#pragma unroll
      for (int j = 0; j < 4; ++j) {
        int row = m * 16 + ((lane >> 4) << 2) + j;
        P[(((size_t)mat * DKCH + ch) * 64 + row) * 256 + o] = acc[m][n][j];
      }
    }
}

// ---------------- threefry / eps ----------------------------------------------------
__device__ __forceinline__ unsigned rotl32(unsigned v, int s) {
  return (v << s) | (v >> (32 - s));
}
__device__ void threefry(unsigned k0, unsigned k1, unsigned x0, unsigned x1,
                         unsigned& o0, unsigned& o1) {
  unsigned ks2 = k0 ^ k1 ^ 0x1BD11BDAu;
  unsigned a = x0 + k0, b = x1 + k1;
#define TF_RND(rot) { a += b; b = rotl32(b, rot); b ^= a; }
  TF_RND(13) TF_RND(15) TF_RND(26) TF_RND(6)
  a += k1; b += ks2 + 1u;
  TF_RND(17) TF_RND(29) TF_RND(16) TF_RND(24)
  a += ks2; b += k0 + 2u;
  TF_RND(13) TF_RND(15) TF_RND(26) TF_RND(6)
  a += k0; b += k1 + 3u;
  TF_RND(17) TF_RND(29) TF_RND(16) TF_RND(24)
  a += k1; b += ks2 + 4u;
  TF_RND(13) TF_RND(15) TF_RND(26) TF_RND(6)
  a += ks2; b += k0 + 5u;
#undef TF_RND
  o0 = a; o1 = b;
}

__device__ float u32_to_normal(unsigned bits) {
  unsigned fb = (bits >> 9) | 0x3F800000u;
  float f = __uint_as_float(fb) - 1.0f;
  const float lo = -0.99999994f;
  float u = f * 2.0f + lo;
  u = fmaxf(lo, u);
  float w = -log1pf(-u * u);
  float p;
  if (w < 5.0f) {
    w -= 2.5f;
    p = 2.81022636e-08f;
    p = fmaf(p, w, 3.43273939e-07f);
    p = fmaf(p, w, -3.5233877e-06f);
    p = fmaf(p, w, -4.39150654e-06f);
    p = fmaf(p, w, 0.00021858087f);
    p = fmaf(p, w, -0.00125372503f);
    p = fmaf(p, w, -0.00417768164f);
    p = fmaf(p, w, 0.246640727f);
    p = fmaf(p, w, 1.50140941f);
  } else {
    w = sqrtf(w) - 3.0f;
    p = -0.000200214257f;
    p = fmaf(p, w, 0.000100950558f);
    p = fmaf(p, w, 0.00134934322f);
    p = fmaf(p, w, -0.00367342844f);
    p = fmaf(p, w, 0.00573950773f);
    p = fmaf(p, w, -0.0076224613f);
    p = fmaf(p, w, 0.00943887047f);
    p = fmaf(p, w, 1.00167406f);
    p = fmaf(p, w, 2.83297682f);
  }
  return 1.41421354f * (p * u);
}

__global__ __launch_bounds__(256) void eps_kernel(float* __restrict__ eps) {
  int b = blockIdx.x;
  int o = threadIdx.x;
  unsigned k0, k1;
  threefry(0u, 0u, 0u, 1234u, k0, k1);
  float s = 0.f;
  for (int smp = 0; smp < 50; ++smp) {
    unsigned idx = ((unsigned)smp * 64u + (unsigned)b) * 256u + (unsigned)o;
    unsigned o0, o1, bits;
#if EPS_MODE == 0
    threefry(k0, k1, 0u, idx, o0, o1);
    bits = o0 ^ o1;
#else
    unsigned pp = idx % 409600u, half = idx / 409600u;
    threefry(k0, k1, pp, pp + 409600u, o0, o1);
    bits = half ? o1 : o0;
#endif
    s += u32_to_normal(bits);
  }
  eps[b * 256 + o] = s / 50.0f;
}

// ---------------- final reduce + heads + reparam ------------------------------------
__global__ __launch_bounds__(256) void final_kernel(const float* __restrict__ P,
                                                    const float* __restrict__ bmu,
                                                    const float* __restrict__ blv,
                                                    const float* __restrict__ eps,
                                                    float* __restrict__ out) {
  int b = blockIdx.x, o = threadIdx.x;
  float smu = 0.f, slv = 0.f;
  for (int ch = 0; ch < DKCH; ++ch) {
    smu += P[(((size_t)0 * DKCH + ch) * 64 + b) * 256 + o];
    slv += P[(((size_t)1 * DKCH + ch) * 64 + b) * 256 + o];
  }
  float mu = sigm(smu + bmu[o]);
  float lv = sigm(slv + blv[o]);
  float z = mu + eps[b * 256 + o] * expf(0.5f * lv);
  out[b * 256 + o] = z;
  out[16384 + b * 256 + o] = mu;
  out[32768 + b * 256 + o] = lv;
}

// ------------------------------------------------------------------------------------
extern "C" void kernel_launch(void* const* d_in, const int* in_sizes, int n_in,
                              void* d_out, int out_size, void* d_ws, size_t ws_size,
                              hipStream_t stream) {
  (void)in_sizes; (void)n_in; (void)out_size; (void)ws_size;
  const float* xs  = (const float*)d_in[0];
  const float* adj = (const float*)d_in[1];
  const float* Wz0 = (const float*)d_in[2];  const float* bz0 = (const float*)d_in[3];
  const float* Wr0 = (const float*)d_in[4];  const float* br0 = (const float*)d_in[5];
  const float* Wn0 = (const float*)d_in[6];  const float* bn0 = (const float*)d_in[7];
  const float* Wz1 = (const float*)d_in[8];  const float* bz1 = (const float*)d_in[9];
  const float* Wr1 = (const float*)d_in[10]; const float* br1 = (const float*)d_in[11];
  const float* Wn1 = (const float*)d_in[12]; const float* bn1 = (const float*)d_in[13];
  const float* Wmu = (const float*)d_in[14]; const float* bmu = (const float*)d_in[15];
  const float* Wlv = (const float*)d_in[16]; const float* blv = (const float*)d_in[17];

  float* ws = (float*)d_ws;
  u16*  adjB  = (u16*)(ws);                  // 0.0  (0.5)
  u16*  xsB   = (u16*)(ws + MF / 2);         // 0.5  (0.5)
  float* AXv  = ws + 1 * MF;                 // 1.0  (1.0)
  u16*  h1T   = (u16*)(ws + 2 * MF);         // 2.0  (2.0)
  u16*  h2T   = (u16*)(ws + 4 * MF);         // 4.0  (4.0)
  u16*  z0T   = (u16*)(ws + 8 * MF);         // 8.0  (2.0)
  u16*  z1T   = (u16*)(ws + 10 * MF);        // 10.0 (4.0)
  u16*  rh0T  = (u16*)(ws + 14 * MF);        // 14.0 (2.0)
  u16*  rh1T  = (u16*)(ws + 16 * MF);        // 16.0 (4.0)
  u16*  AH1   = (u16*)(ws + 20 * MF);        // 20.0 (2.0)
  u16*  AH2   = (u16*)(ws + 22 * MF);        // 22.0 (4.0)
  u16*  WTb   = (u16*)(ws + 26 * MF);        // 26.0 (0.125)
  // post-loop aliases:
  u16*  X     = (u16*)(ws + 8 * MF);         // 8.0  (6.0)
  float* P    = ws + 16 * MF;                // 16.0 (16.78) dense partials (DKCH=512)
  float* EPS  = ws + 33 * MF;                // 33.0

  u16* WzrT0 = WTb;
  u16* WnT0  = WTb + 8192;
  u16* WzrT1 = WTb + 12288;
  u16* WnT1  = WTb + 61440;

  // zero only the buffers read before first write: h2T and AH2
  hipMemsetAsync(ws + 4 * MF, 0, 4 * MF * sizeof(float), stream);
  hipMemsetAsync(ws + 22 * MF, 0, 4 * MF * sizeof(float), stream);

  cast_bf16<<<1024, 256, 0, stream>>>(adj, adjB, 1 << 20);
  cast_bf16<<<1024, 256, 0, stream>>>(xs, xsB, 1 << 20);
  prep_wt<<<dim3(192, 4), 256, 0, stream>>>(Wz0, Wr0, Wn0, Wz1, Wr1, Wn1,
                                            WzrT0, WnT0, WzrT1, WnT1);

  // AX[t][b][n] for all t
  adj_mfma<1, 0, 4><<<dim3(8, 8), 256, 0, stream>>>(adjB, xsB, AXv);

  // prologue: t=0 layer-0 closed form (adj@(r*h)=0 since h1=0)
  init0<<<dim3(64, 4), 256, 0, stream>>>(AXv, Wz0, bz0, Wn0, bn0, h1T);

  for (int t = 0; t < T; ++t) {
    const float* AXn = AXv + (size_t)((t + 1 < T) ? t + 1 : t) * 65536;
    // AH1 = adj@h1_new ; zr1(t) ; zr0(t+1)
    ah1_zr<<<dim3(32, 16), 256, 0, stream>>>(
        adjB, h1T, AH2, h2T, WzrT1, bz1, br1, WzrT0, bz0, br0,
        AXn, Wz0, Wr0, AH1, z1T, rh1T, z0T, rh0T, (t + 1 < T) ? 1 : 0);
    // layer 1 update
    adj_ngate<128, 0, 4><<<dim3(64, 8), 256, 0, stream>>>(
        adjB, rh1T, WnT1, bn1, nullptr, nullptr, AH1, z1T, h2T);
    // AH2(t) [for step t+1] overlapped with layer-0 update of step t+1
    if (t + 1 < T)
      combo_tail<<<1024, 256, 0, stream>>>(adjB, h2T, AH2, rh0T, WnT0, bn0,
                                           AXn, Wn0, z0T, h1T);
  }

  // dense heads
  transpose_x<<<dim3(64, 8), 256, 0, stream>>>(h1T, h2T, X);
  dense_mfma4<<<dim3(2, DKCH, 2), 256, 0, stream>>>(X, Wmu, Wlv, P);
  eps_kernel<<<64, 256, 0, stream>>>(EPS);
  final_kernel<<<64, 256, 0, stream>>>(P, bmu, blv, EPS, (float*)d_out);
}